// Round 5
// baseline (1224.757 us; speedup 1.0000x reference)
//
#include <hip/hip_runtime.h>
#include <math.h>

#define EPS_MSG 1e-7f

typedef float v2f __attribute__((ext_vector_type(2)));
typedef float v4f __attribute__((ext_vector_type(4)));

static __device__ inline v2f sp(float a) { v2f r; r.x = a; r.y = a; return r; }

// ---------------------------------------------------------------- CSR build
__global__ void zero2_kernel(int* __restrict__ a, int* __restrict__ b, int n) {
    int i = blockIdx.x * 256 + threadIdx.x;
    if (i < n) { a[i] = 0; b[i] = 0; }
}

__global__ void deg_kernel(const int* __restrict__ ei, int* __restrict__ deg, int E) {
    int e = blockIdx.x * 256 + threadIdx.x;
    if (e < E) atomicAdd(&deg[ei[E + e]], 1);
}

// multi-block scan: (1) per-1024-chunk exclusive scan + chunk totals
__global__ __launch_bounds__(1024)
void scan1_kernel(const int* __restrict__ deg, int* __restrict__ offs,
                  int* __restrict__ bsum, int n) {
    __shared__ int sh[1024];
    int tid = threadIdx.x;
    int i = blockIdx.x * 1024 + tid;
    int v = (i < n) ? deg[i] : 0;
    sh[tid] = v;
    __syncthreads();
    for (int off = 1; off < 1024; off <<= 1) {
        int t = (tid >= off) ? sh[tid - off] : 0;
        __syncthreads();
        sh[tid] += t;
        __syncthreads();
    }
    if (i < n) offs[i] = sh[tid] - v;
    if (tid == 1023) bsum[blockIdx.x] = sh[tid];
}

// (2) one-wave exclusive scan of chunk totals (loops in chunks of 64); total -> bsum[nb]
__global__ __launch_bounds__(64)
void scan2_kernel(int* __restrict__ bsum, int nb) {
    int lane = threadIdx.x;
    int carry = 0;
    for (int base = 0; base < nb; base += 64) {
        int v = (base + lane < nb) ? bsum[base + lane] : 0;
        int incl = v;
#pragma unroll
        for (int off = 1; off < 64; off <<= 1) {
            int t = __shfl_up(incl, off, 64);
            if (lane >= off) incl += t;
        }
        if (base + lane < nb) bsum[base + lane] = incl - v + carry;
        carry += __shfl(incl, 63, 64);
    }
    if (lane == 0) bsum[nb] = carry;
}

// (3) add chunk offsets; offs[n] = total
__global__ void scan3_kernel(int* __restrict__ offs, const int* __restrict__ bsum, int n) {
    int i = blockIdx.x * 256 + threadIdx.x;
    if (i < n) offs[i] += bsum[i >> 10];
    else if (i == n) offs[n] = bsum[(n + 1023) >> 10];
}

__global__ void scatter_kernel(const int* __restrict__ ei, const float* __restrict__ edge_attr,
                               const int* __restrict__ offs, int* __restrict__ fill,
                               int* __restrict__ src_perm, float* __restrict__ attr_perm, int E) {
    int e = blockIdx.x * 256 + threadIdx.x;
    if (e >= E) return;
    int s = ei[e];
    int d = ei[E + e];
    int pos = offs[d] + atomicAdd(&fill[d], 1);
    src_perm[pos] = s;
    const float4* a = (const float4*)&edge_attr[(size_t)e * 16];
    float4* b = (float4*)&attr_perm[(size_t)pos * 16];
    b[0] = a[0]; b[1] = a[1]; b[2] = a[2]; b[3] = a[3];
}

// ---------------------------------------------------------------- node encoder: X = x @ W(64x128) + b
__global__ __launch_bounds__(256)
void encode_kernel(const float* __restrict__ x, const float* __restrict__ W,
                   const float* __restrict__ b, float* __restrict__ out, int N) {
    __shared__ __align__(16) float Xa[32][64];
    int tid = threadIdx.x;
    int node0 = blockIdx.x * 32;
    {
        int row = tid >> 3;
        int col = (tid & 7) * 8;
        float4 v0 = make_float4(0, 0, 0, 0), v1 = make_float4(0, 0, 0, 0);
        if (node0 + row < N) {
            const float* sp_ = &x[(size_t)(node0 + row) * 64 + col];
            v0 = *(const float4*)sp_;
            v1 = *(const float4*)(sp_ + 4);
        }
        *(float4*)&Xa[row][col] = v0;
        *(float4*)&Xa[row][col + 4] = v1;
    }
    __syncthreads();
    int tx = tid & 31, rg = tid >> 5;
    int c = tx * 4;
    v2f ba = *(const v2f*)&b[c];
    v2f bb = *(const v2f*)&b[c + 2];
    v2f acc[4][2];
#pragma unroll
    for (int i = 0; i < 4; ++i) { acc[i][0] = ba; acc[i][1] = bb; }
    for (int k = 0; k < 64; k += 4) {
        v4f W0 = *(const v4f*)&W[(k + 0) * 128 + c];
        v4f W1r = *(const v4f*)&W[(k + 1) * 128 + c];
        v4f W2r = *(const v4f*)&W[(k + 2) * 128 + c];
        v4f W3r = *(const v4f*)&W[(k + 3) * 128 + c];
#pragma unroll
        for (int i = 0; i < 4; ++i) {
            v4f xv = *(const v4f*)&Xa[rg * 4 + i][k];
            acc[i][0] = __builtin_elementwise_fma(sp(xv.x), W0.xy, acc[i][0]);
            acc[i][1] = __builtin_elementwise_fma(sp(xv.x), W0.zw, acc[i][1]);
            acc[i][0] = __builtin_elementwise_fma(sp(xv.y), W1r.xy, acc[i][0]);
            acc[i][1] = __builtin_elementwise_fma(sp(xv.y), W1r.zw, acc[i][1]);
            acc[i][0] = __builtin_elementwise_fma(sp(xv.z), W2r.xy, acc[i][0]);
            acc[i][1] = __builtin_elementwise_fma(sp(xv.z), W2r.zw, acc[i][1]);
            acc[i][0] = __builtin_elementwise_fma(sp(xv.w), W3r.xy, acc[i][0]);
            acc[i][1] = __builtin_elementwise_fma(sp(xv.w), W3r.zw, acc[i][1]);
        }
    }
#pragma unroll
    for (int i = 0; i < 4; ++i) {
        int row = node0 + rg * 4 + i;
        if (row < N) {
            float4 o = make_float4(acc[i][0].x, acc[i][0].y, acc[i][1].x, acc[i][1].y);
            *(float4*)&out[(size_t)row * 128 + c] = o;
        }
    }
}

// ---------------------------------------------------------------- LN(128) + relu
__global__ __launch_bounds__(256)
void ln_relu_kernel(const float* __restrict__ x, const float* __restrict__ g,
                    const float* __restrict__ b, float* __restrict__ out, int N) {
    int lane = threadIdx.x & 63;
    int node = blockIdx.x * 4 + (threadIdx.x >> 6);
    if (node >= N) return;
    int c0 = lane * 2;
    float2 xv = *(const float2*)&x[(size_t)node * 128 + c0];
    float s = xv.x + xv.y;
    float q = xv.x * xv.x + xv.y * xv.y;
#pragma unroll
    for (int m = 1; m < 64; m <<= 1) { s += __shfl_xor(s, m, 64); q += __shfl_xor(q, m, 64); }
    float mu = s * (1.f / 128.f);
    float var = q * (1.f / 128.f) - mu * mu;
    float rs = rsqrtf(var + 1e-5f);
    float ox = fmaxf((xv.x - mu) * rs * g[c0] + b[c0], 0.f);
    float oy = fmaxf((xv.y - mu) * rs * g[c0 + 1] + b[c0 + 1], 0.f);
    float2 o; o.x = ox; o.y = oy;
    *(float2*)&out[(size_t)node * 128 + c0] = o;
}

// ---------------------------------------------------------------- GENConv aggregation
// Direct exp (no max-subtraction): logits bounded for LN-bounded inputs -> exact softmax ratio.
// attr row is wave-uniform -> scalar loads via readfirstlane.
__global__ __launch_bounds__(256, 4)
void conv_kernel(const float* __restrict__ pre, const float* __restrict__ attr_perm,
                 const int* __restrict__ src_perm, const int* __restrict__ offs,
                 const float* __restrict__ edge_W, const float* __restrict__ edge_b,
                 const float* __restrict__ ts, int layer,
                 float* __restrict__ convout, int N) {
    int lane = threadIdx.x & 63;
    int node = blockIdx.x * 4 + (threadIdx.x >> 6);
    if (node >= N) return;
    int c0 = lane * 2;
    v2f wE[16];
#pragma unroll
    for (int k = 0; k < 16; ++k) {
        wE[k].x = edge_W[k * 128 + c0];
        wE[k].y = edge_W[k * 128 + c0 + 1];
    }
    v2f eb; eb.x = edge_b[c0]; eb.y = edge_b[c0 + 1];
    float t = ts[layer];
    int i0 = offs[node], i1 = offs[node + 1];
    v2f xself = *(const v2f*)&pre[(size_t)node * 128 + c0];
    float sx = 0.f, sy = 0.f, wx = 0.f, wy = 0.f;
    for (int i = i0; i < i1; ++i) {
        int iu = __builtin_amdgcn_readfirstlane(i);
        int sn = src_perm[iu];
        const v4f* ar = (const v4f*)(attr_perm + (size_t)iu * 16);
        v4f A0 = ar[0];
        v4f A1 = ar[1];
        v4f A2 = ar[2];
        v4f A3 = ar[3];
        v2f xv = *(const v2f*)&pre[(size_t)sn * 128 + c0];
        v2f ea = eb;
        ea = __builtin_elementwise_fma(sp(A0.x), wE[0], ea);
        ea = __builtin_elementwise_fma(sp(A0.y), wE[1], ea);
        ea = __builtin_elementwise_fma(sp(A0.z), wE[2], ea);
        ea = __builtin_elementwise_fma(sp(A0.w), wE[3], ea);
        ea = __builtin_elementwise_fma(sp(A1.x), wE[4], ea);
        ea = __builtin_elementwise_fma(sp(A1.y), wE[5], ea);
        ea = __builtin_elementwise_fma(sp(A1.z), wE[6], ea);
        ea = __builtin_elementwise_fma(sp(A1.w), wE[7], ea);
        ea = __builtin_elementwise_fma(sp(A2.x), wE[8], ea);
        ea = __builtin_elementwise_fma(sp(A2.y), wE[9], ea);
        ea = __builtin_elementwise_fma(sp(A2.z), wE[10], ea);
        ea = __builtin_elementwise_fma(sp(A2.w), wE[11], ea);
        ea = __builtin_elementwise_fma(sp(A3.x), wE[12], ea);
        ea = __builtin_elementwise_fma(sp(A3.y), wE[13], ea);
        ea = __builtin_elementwise_fma(sp(A3.z), wE[14], ea);
        ea = __builtin_elementwise_fma(sp(A3.w), wE[15], ea);
        float mgx = fmaxf(xv.x + ea.x, 0.f) + EPS_MSG;
        float mgy = fmaxf(xv.y + ea.y, 0.f) + EPS_MSG;
        float ex = __expf(mgx * t);
        float ey = __expf(mgy * t);
        sx += ex; sy += ey;
        wx = fmaf(ex, mgx, wx);
        wy = fmaf(ey, mgy, wy);
    }
    float ax = (sx > 0.f) ? wx / sx : 0.f;
    float ay = (sy > 0.f) ? wy / sy : 0.f;
    v2f o; o.x = ax + xself.x; o.y = ay + xself.y;
    *(v2f*)&convout[(size_t)node * 128 + c0] = o;
}

// ---------------------------------------------------------------- fused MLP: Lin(128->256)+LN+relu+Lin(256->128) (+res)
// 16 nodes/block: Xa 8KB + Xh 16KB = 24KB LDS -> ~6 blocks/CU (vs 2 at 48KB).
template <int RES>
__global__ __launch_bounds__(256, 6)
void mlp_kernel(const float* __restrict__ convin, const float* __restrict__ W1,
                const float* __restrict__ b1, const float* __restrict__ g1,
                const float* __restrict__ be1, const float* __restrict__ W2,
                const float* __restrict__ b2, const float* __restrict__ xold,
                float* __restrict__ xnew, int N) {
    __shared__ __align__(16) float Xa[16][128];
    __shared__ __align__(16) float Xh[16][256];
    int tid = threadIdx.x;
    int node0 = blockIdx.x * 16;
    {
        int row = tid >> 4;
        int col = (tid & 15) * 8;
        float4 v0 = make_float4(0, 0, 0, 0), v1 = v0;
        if (node0 + row < N) {
            const float4* sp_ = (const float4*)&convin[(size_t)(node0 + row) * 128 + col];
            v0 = sp_[0]; v1 = sp_[1];
        }
        *(float4*)&Xa[row][col + 0] = v0;
        *(float4*)&Xa[row][col + 4] = v1;
    }
    __syncthreads();
    // GEMM1: 16x256 = Xa(16x128) @ W1(128x256); wave ty owns 4 rows, lane owns 4 cols
    {
        int tx = tid & 63, ty = tid >> 6;
        int c = tx * 4;
        v2f b1a = *(const v2f*)&b1[c];
        v2f b1b = *(const v2f*)&b1[c + 2];
        v2f acc[4][2];
#pragma unroll
        for (int i = 0; i < 4; ++i) { acc[i][0] = b1a; acc[i][1] = b1b; }
        for (int k = 0; k < 128; k += 4) {
            v4f W0 = *(const v4f*)&W1[(size_t)(k + 0) * 256 + c];
            v4f W1r = *(const v4f*)&W1[(size_t)(k + 1) * 256 + c];
            v4f W2r = *(const v4f*)&W1[(size_t)(k + 2) * 256 + c];
            v4f W3r = *(const v4f*)&W1[(size_t)(k + 3) * 256 + c];
#pragma unroll
            for (int i = 0; i < 4; ++i) {
                v4f xv = *(const v4f*)&Xa[ty * 4 + i][k];
                acc[i][0] = __builtin_elementwise_fma(sp(xv.x), W0.xy, acc[i][0]);
                acc[i][1] = __builtin_elementwise_fma(sp(xv.x), W0.zw, acc[i][1]);
                acc[i][0] = __builtin_elementwise_fma(sp(xv.y), W1r.xy, acc[i][0]);
                acc[i][1] = __builtin_elementwise_fma(sp(xv.y), W1r.zw, acc[i][1]);
                acc[i][0] = __builtin_elementwise_fma(sp(xv.z), W2r.xy, acc[i][0]);
                acc[i][1] = __builtin_elementwise_fma(sp(xv.z), W2r.zw, acc[i][1]);
                acc[i][0] = __builtin_elementwise_fma(sp(xv.w), W3r.xy, acc[i][0]);
                acc[i][1] = __builtin_elementwise_fma(sp(xv.w), W3r.zw, acc[i][1]);
            }
        }
        // LN(256) + relu per row (reduce across the 64 lanes of this wave)
        v2f g1a = *(const v2f*)&g1[c];
        v2f g1b = *(const v2f*)&g1[c + 2];
        v2f bea = *(const v2f*)&be1[c];
        v2f beb = *(const v2f*)&be1[c + 2];
#pragma unroll
        for (int i = 0; i < 4; ++i) {
            float s = acc[i][0].x + acc[i][0].y + acc[i][1].x + acc[i][1].y;
            float q = acc[i][0].x * acc[i][0].x + acc[i][0].y * acc[i][0].y +
                      acc[i][1].x * acc[i][1].x + acc[i][1].y * acc[i][1].y;
#pragma unroll
            for (int m = 1; m < 64; m <<= 1) { s += __shfl_xor(s, m, 64); q += __shfl_xor(q, m, 64); }
            float mu = s * (1.f / 256.f);
            float var = q * (1.f / 256.f) - mu * mu;
            float rs = rsqrtf(var + 1e-5f);
            float h0 = fmaxf((acc[i][0].x - mu) * rs * g1a.x + bea.x, 0.f);
            float h1 = fmaxf((acc[i][0].y - mu) * rs * g1a.y + bea.y, 0.f);
            float h2 = fmaxf((acc[i][1].x - mu) * rs * g1b.x + beb.x, 0.f);
            float h3 = fmaxf((acc[i][1].y - mu) * rs * g1b.y + beb.y, 0.f);
            *(float4*)&Xh[ty * 4 + i][c] = make_float4(h0, h1, h2, h3);
        }
    }
    __syncthreads();
    // GEMM2: 16x128 = Xh(16x256) @ W2(256x128); 32-lane group rg owns 2 rows, lane owns 4 cols
    {
        int tx2 = tid & 31, rg = tid >> 5;
        int c2 = tx2 * 4;
        v2f b2a = *(const v2f*)&b2[c2];
        v2f b2b = *(const v2f*)&b2[c2 + 2];
        v2f acc[2][2];
#pragma unroll
        for (int i = 0; i < 2; ++i) { acc[i][0] = b2a; acc[i][1] = b2b; }
        for (int k = 0; k < 256; k += 4) {
            v4f W0 = *(const v4f*)&W2[(size_t)(k + 0) * 128 + c2];
            v4f W1r = *(const v4f*)&W2[(size_t)(k + 1) * 128 + c2];
            v4f W2r = *(const v4f*)&W2[(size_t)(k + 2) * 128 + c2];
            v4f W3r = *(const v4f*)&W2[(size_t)(k + 3) * 128 + c2];
#pragma unroll
            for (int i = 0; i < 2; ++i) {
                v4f xv = *(const v4f*)&Xh[rg * 2 + i][k];
                acc[i][0] = __builtin_elementwise_fma(sp(xv.x), W0.xy, acc[i][0]);
                acc[i][1] = __builtin_elementwise_fma(sp(xv.x), W0.zw, acc[i][1]);
                acc[i][0] = __builtin_elementwise_fma(sp(xv.y), W1r.xy, acc[i][0]);
                acc[i][1] = __builtin_elementwise_fma(sp(xv.y), W1r.zw, acc[i][1]);
                acc[i][0] = __builtin_elementwise_fma(sp(xv.z), W2r.xy, acc[i][0]);
                acc[i][1] = __builtin_elementwise_fma(sp(xv.z), W2r.zw, acc[i][1]);
                acc[i][0] = __builtin_elementwise_fma(sp(xv.w), W3r.xy, acc[i][0]);
                acc[i][1] = __builtin_elementwise_fma(sp(xv.w), W3r.zw, acc[i][1]);
            }
        }
#pragma unroll
        for (int i = 0; i < 2; ++i) {
            int row = node0 + rg * 2 + i;
            if (row < N) {
                float4 o = make_float4(acc[i][0].x, acc[i][0].y, acc[i][1].x, acc[i][1].y);
                if (RES) {
                    float4 xo = *(const float4*)&xold[(size_t)row * 128 + c2];
                    o.x += xo.x; o.y += xo.y; o.z += xo.z; o.w += xo.w;
                }
                *(float4*)&xnew[(size_t)row * 128 + c2] = o;
            }
        }
    }
}

// ---------------------------------------------------------------- head
__global__ __launch_bounds__(256)
void head_kernel(const float* __restrict__ pre, const float* __restrict__ gf,
                 const float* __restrict__ W0, const float* __restrict__ b0,
                 const float* __restrict__ W1h, const float* __restrict__ b1h,
                 float* __restrict__ out, int N) {
    __shared__ __align__(16) float V[8][132];
    int tid = threadIdx.x;
    int node0 = blockIdx.x * 8;
    int tx = tid & 31, rg = tid >> 5;
    {
        int col = tx * 4;
        float4 v = make_float4(0, 0, 0, 0);
        int node = node0 + rg;
        if (node < N) v = *(const float4*)&pre[(size_t)node * 128 + col];
        *(float4*)&V[rg][col] = v;
        if (tx == 0) {
            int a = node / 1000;
            int i0 = 2 * a, i1 = 2 * a + 1;
            float f0 = 0.f, f1 = 0.f;
            if (node < N) {
                f0 = (i0 < 50) ? gf[i0 * 2] : gf[(i0 - 50) * 2 + 1];
                f1 = (i1 < 50) ? gf[i1 * 2] : gf[(i1 - 50) * 2 + 1];
            }
            V[rg][128] = f0;
            V[rg][129] = f1;
        }
    }
    __syncthreads();
    int c = tx * 4;
    float4 b0v = *(const float4*)&b0[c];
    float a0 = b0v.x, a1 = b0v.y, a2 = b0v.z, a3 = b0v.w;
    for (int k = 0; k < 130; ++k) {
        float vk = V[rg][k];
        float4 w = *(const float4*)&W0[k * 128 + c];
        a0 = fmaf(vk, w.x, a0);
        a1 = fmaf(vk, w.y, a1);
        a2 = fmaf(vk, w.z, a2);
        a3 = fmaf(vk, w.w, a3);
    }
    a0 = fmaxf(a0, 0.f); a1 = fmaxf(a1, 0.f); a2 = fmaxf(a2, 0.f); a3 = fmaxf(a3, 0.f);
    float4 wh = *(const float4*)&W1h[c];
    float p = a0 * wh.x + a1 * wh.y + a2 * wh.z + a3 * wh.w;
#pragma unroll
    for (int m = 1; m < 32; m <<= 1) p += __shfl_xor(p, m, 64);
    int node = node0 + rg;
    if (tx == 0 && node < N) out[node] = p + b1h[0];
}

// ---------------------------------------------------------------- launch
extern "C" void kernel_launch(void* const* d_in, const int* in_sizes, int n_in,
                              void* d_out, int out_size, void* d_ws, size_t ws_size,
                              hipStream_t stream) {
    const float* x_in    = (const float*)d_in[0];
    const int*   ei      = (const int*)d_in[1];
    const float* edge_attr = (const float*)d_in[2];
    const float* gf      = (const float*)d_in[3];
    const float* node_W  = (const float*)d_in[4];
    const float* node_b  = (const float*)d_in[5];
    const float* edge_W  = (const float*)d_in[6];
    const float* edge_b  = (const float*)d_in[7];
    const float* ts      = (const float*)d_in[8];
    const float* W1s     = (const float*)d_in[9];
    const float* b1s     = (const float*)d_in[10];
    const float* g1s     = (const float*)d_in[11];
    const float* be1s    = (const float*)d_in[12];
    const float* W2s     = (const float*)d_in[13];
    const float* b2s     = (const float*)d_in[14];
    const float* ln_gs   = (const float*)d_in[15];
    const float* ln_bs   = (const float*)d_in[16];
    const float* hW0     = (const float*)d_in[17];
    const float* hb0     = (const float*)d_in[18];
    const float* hW1     = (const float*)d_in[19];
    const float* hb1     = (const float*)d_in[20];

    const int N = in_sizes[0] / 64;
    const int E = in_sizes[1] / 2;
    const int NB = (N + 1023) / 1024;

    char* ws = (char*)d_ws;
    size_t off = 0;
    auto alloc = [&](size_t bytes) -> void* {
        void* p = ws + off;
        off = (off + bytes + 255) & ~(size_t)255;
        return p;
    };
    float* X     = (float*)alloc((size_t)N * 128 * 4);
    float* PRE   = (float*)alloc((size_t)N * 128 * 4);
    float* CONV  = (float*)alloc((size_t)N * 128 * 4);
    float* ATTRP = (float*)alloc((size_t)E * 16 * 4);
    int* SRCP    = (int*)alloc((size_t)E * 4);
    int* DEG     = (int*)alloc((size_t)N * 4);
    int* FILL    = (int*)alloc((size_t)N * 4);
    int* OFFS    = (int*)alloc((size_t)(N + 1) * 4);
    int* BSUM    = (int*)alloc((size_t)(NB + 1) * 4);

    // CSR build (per call; deterministic set of work)
    zero2_kernel<<<(N + 255) / 256, 256, 0, stream>>>(DEG, FILL, N);
    deg_kernel<<<(E + 255) / 256, 256, 0, stream>>>(ei, DEG, E);
    scan1_kernel<<<NB, 1024, 0, stream>>>(DEG, OFFS, BSUM, N);
    scan2_kernel<<<1, 64, 0, stream>>>(BSUM, NB);
    scan3_kernel<<<(N + 256) / 256, 256, 0, stream>>>(OFFS, BSUM, N);
    scatter_kernel<<<(E + 255) / 256, 256, 0, stream>>>(ei, edge_attr, OFFS, FILL, SRCP, ATTRP, E);

    encode_kernel<<<(N + 31) / 32, 256, 0, stream>>>(x_in, node_W, node_b, X, N);

    for (int layer = 0; layer < 4; ++layer) {
        const float* pre = X;
        if (layer > 0) {
            ln_relu_kernel<<<(N + 3) / 4, 256, 0, stream>>>(X, ln_gs + 128 * layer, ln_bs + 128 * layer, PRE, N);
            pre = PRE;
        }
        conv_kernel<<<(N + 3) / 4, 256, 0, stream>>>(pre, ATTRP, SRCP, OFFS, edge_W, edge_b, ts, layer, CONV, N);
        const float* W1 = W1s + (size_t)layer * 128 * 256;
        const float* W2 = W2s + (size_t)layer * 256 * 128;
        if (layer == 0)
            mlp_kernel<0><<<(N + 15) / 16, 256, 0, stream>>>(CONV, W1, b1s + layer * 256, g1s + layer * 256,
                                                             be1s + layer * 256, W2, b2s + layer * 128, X, X, N);
        else
            mlp_kernel<1><<<(N + 15) / 16, 256, 0, stream>>>(CONV, W1, b1s + layer * 256, g1s + layer * 256,
                                                             be1s + layer * 256, W2, b2s + layer * 128, X, X, N);
    }

    ln_relu_kernel<<<(N + 3) / 4, 256, 0, stream>>>(X, ln_gs, ln_bs, PRE, N);
    head_kernel<<<(N + 7) / 8, 256, 0, stream>>>(PRE, gf, hW0, hb0, hW1, hb1, (float*)d_out, N);
}

// Round 6
// 985.464 us; speedup vs baseline: 1.2428x; 1.2428x over previous
//
#include <hip/hip_runtime.h>
#include <math.h>

#define EPS_MSG 1e-7f

typedef float v2f __attribute__((ext_vector_type(2)));
typedef float v4f __attribute__((ext_vector_type(4)));

static __device__ inline v2f sp(float a) { v2f r; r.x = a; r.y = a; return r; }

// ---------------------------------------------------------------- CSR build
__global__ void zero2_kernel(int* __restrict__ a, int* __restrict__ b, int n) {
    int i = blockIdx.x * 256 + threadIdx.x;
    if (i < n) { a[i] = 0; b[i] = 0; }
}

__global__ void deg_kernel(const int* __restrict__ ei, int* __restrict__ deg, int E) {
    int e = blockIdx.x * 256 + threadIdx.x;
    if (e < E) atomicAdd(&deg[ei[E + e]], 1);
}

// multi-block scan: (1) per-1024-chunk exclusive scan + chunk totals
__global__ __launch_bounds__(1024)
void scan1_kernel(const int* __restrict__ deg, int* __restrict__ offs,
                  int* __restrict__ bsum, int n) {
    __shared__ int sh[1024];
    int tid = threadIdx.x;
    int i = blockIdx.x * 1024 + tid;
    int v = (i < n) ? deg[i] : 0;
    sh[tid] = v;
    __syncthreads();
    for (int off = 1; off < 1024; off <<= 1) {
        int t = (tid >= off) ? sh[tid - off] : 0;
        __syncthreads();
        sh[tid] += t;
        __syncthreads();
    }
    if (i < n) offs[i] = sh[tid] - v;
    if (tid == 1023) bsum[blockIdx.x] = sh[tid];
}

// (2) one-wave exclusive scan of chunk totals; total -> bsum[nb]
__global__ __launch_bounds__(64)
void scan2_kernel(int* __restrict__ bsum, int nb) {
    int lane = threadIdx.x;
    int carry = 0;
    for (int base = 0; base < nb; base += 64) {
        int v = (base + lane < nb) ? bsum[base + lane] : 0;
        int incl = v;
#pragma unroll
        for (int off = 1; off < 64; off <<= 1) {
            int t = __shfl_up(incl, off, 64);
            if (lane >= off) incl += t;
        }
        if (base + lane < nb) bsum[base + lane] = incl - v + carry;
        carry += __shfl(incl, 63, 64);
    }
    if (lane == 0) bsum[nb] = carry;
}

// (3) add chunk offsets; offs[n] = total
__global__ void scan3_kernel(int* __restrict__ offs, const int* __restrict__ bsum, int n) {
    int i = blockIdx.x * 256 + threadIdx.x;
    if (i < n) offs[i] += bsum[i >> 10];
    else if (i == n) offs[n] = bsum[(n + 1023) >> 10];
}

__global__ void scatter_kernel(const int* __restrict__ ei, const float* __restrict__ edge_attr,
                               const int* __restrict__ offs, int* __restrict__ fill,
                               int* __restrict__ src_perm, float* __restrict__ attr_perm, int E) {
    int e = blockIdx.x * 256 + threadIdx.x;
    if (e >= E) return;
    int s = ei[e];
    int d = ei[E + e];
    int pos = offs[d] + atomicAdd(&fill[d], 1);
    src_perm[pos] = s;
    const float4* a = (const float4*)&edge_attr[(size_t)e * 16];
    float4* b = (float4*)&attr_perm[(size_t)pos * 16];
    b[0] = a[0]; b[1] = a[1]; b[2] = a[2]; b[3] = a[3];
}

// ---------------------------------------------------------------- node encoder: X = x @ W(64x128) + b
__global__ __launch_bounds__(256)
void encode_kernel(const float* __restrict__ x, const float* __restrict__ W,
                   const float* __restrict__ b, float* __restrict__ out, int N) {
    __shared__ __align__(16) float Xa[32][64];
    int tid = threadIdx.x;
    int node0 = blockIdx.x * 32;
    {
        int row = tid >> 3;
        int col = (tid & 7) * 8;
        float4 v0 = make_float4(0, 0, 0, 0), v1 = make_float4(0, 0, 0, 0);
        if (node0 + row < N) {
            const float* sp_ = &x[(size_t)(node0 + row) * 64 + col];
            v0 = *(const float4*)sp_;
            v1 = *(const float4*)(sp_ + 4);
        }
        *(float4*)&Xa[row][col] = v0;
        *(float4*)&Xa[row][col + 4] = v1;
    }
    __syncthreads();
    int tx = tid & 31, rg = tid >> 5;
    int c = tx * 4;
    v2f ba = *(const v2f*)&b[c];
    v2f bb = *(const v2f*)&b[c + 2];
    v2f acc[4][2];
#pragma unroll
    for (int i = 0; i < 4; ++i) { acc[i][0] = ba; acc[i][1] = bb; }
    for (int k = 0; k < 64; k += 4) {
        v4f W0 = *(const v4f*)&W[(k + 0) * 128 + c];
        v4f W1r = *(const v4f*)&W[(k + 1) * 128 + c];
        v4f W2r = *(const v4f*)&W[(k + 2) * 128 + c];
        v4f W3r = *(const v4f*)&W[(k + 3) * 128 + c];
#pragma unroll
        for (int i = 0; i < 4; ++i) {
            v4f xv = *(const v4f*)&Xa[rg * 4 + i][k];
            acc[i][0] = __builtin_elementwise_fma(sp(xv.x), W0.xy, acc[i][0]);
            acc[i][1] = __builtin_elementwise_fma(sp(xv.x), W0.zw, acc[i][1]);
            acc[i][0] = __builtin_elementwise_fma(sp(xv.y), W1r.xy, acc[i][0]);
            acc[i][1] = __builtin_elementwise_fma(sp(xv.y), W1r.zw, acc[i][1]);
            acc[i][0] = __builtin_elementwise_fma(sp(xv.z), W2r.xy, acc[i][0]);
            acc[i][1] = __builtin_elementwise_fma(sp(xv.z), W2r.zw, acc[i][1]);
            acc[i][0] = __builtin_elementwise_fma(sp(xv.w), W3r.xy, acc[i][0]);
            acc[i][1] = __builtin_elementwise_fma(sp(xv.w), W3r.zw, acc[i][1]);
        }
    }
#pragma unroll
    for (int i = 0; i < 4; ++i) {
        int row = node0 + rg * 4 + i;
        if (row < N) {
            float4 o = make_float4(acc[i][0].x, acc[i][0].y, acc[i][1].x, acc[i][1].y);
            *(float4*)&out[(size_t)row * 128 + c] = o;
        }
    }
}

// ---------------------------------------------------------------- LN(128) + relu
__global__ __launch_bounds__(256)
void ln_relu_kernel(const float* __restrict__ x, const float* __restrict__ g,
                    const float* __restrict__ b, float* __restrict__ out, int N) {
    int lane = threadIdx.x & 63;
    int node = blockIdx.x * 4 + (threadIdx.x >> 6);
    if (node >= N) return;
    int c0 = lane * 2;
    float2 xv = *(const float2*)&x[(size_t)node * 128 + c0];
    float s = xv.x + xv.y;
    float q = xv.x * xv.x + xv.y * xv.y;
#pragma unroll
    for (int m = 1; m < 64; m <<= 1) { s += __shfl_xor(s, m, 64); q += __shfl_xor(q, m, 64); }
    float mu = s * (1.f / 128.f);
    float var = q * (1.f / 128.f) - mu * mu;
    float rs = rsqrtf(var + 1e-5f);
    float ox = fmaxf((xv.x - mu) * rs * g[c0] + b[c0], 0.f);
    float oy = fmaxf((xv.y - mu) * rs * g[c0 + 1] + b[c0 + 1], 0.f);
    float2 o; o.x = ox; o.y = oy;
    *(float2*)&out[(size_t)node * 128 + c0] = o;
}

// ---------------------------------------------------------------- GENConv aggregation
// One wave per node, 2 channels per lane. Edge loop unrolled x2: two independent
// x-gathers + two independent 16-FMA ea-chains in flight per iteration.
__global__ __launch_bounds__(256, 4)
void conv_kernel(const float* __restrict__ pre, const float* __restrict__ attr_perm,
                 const int* __restrict__ src_perm, const int* __restrict__ offs,
                 const float* __restrict__ edge_W, const float* __restrict__ edge_b,
                 const float* __restrict__ ts, int layer,
                 float* __restrict__ convout, int N) {
    int lane = threadIdx.x & 63;
    int node = blockIdx.x * 4 + (threadIdx.x >> 6);
    if (node >= N) return;
    int c0 = lane * 2;
    v2f wE[16];
#pragma unroll
    for (int k = 0; k < 16; ++k) {
        wE[k].x = edge_W[k * 128 + c0];
        wE[k].y = edge_W[k * 128 + c0 + 1];
    }
    v2f eb; eb.x = edge_b[c0]; eb.y = edge_b[c0 + 1];
    float t = ts[layer];
    int i0 = offs[node], i1 = offs[node + 1];
    v2f xself = *(const v2f*)&pre[(size_t)node * 128 + c0];
    float sx = 0.f, sy = 0.f, wx = 0.f, wy = 0.f;
    int i = i0;
    for (; i + 1 < i1; i += 2) {
        int iu = __builtin_amdgcn_readfirstlane(i);
        int sa = src_perm[iu];
        int sb = src_perm[iu + 1];
        const v4f* ar = (const v4f*)(attr_perm + (size_t)iu * 16);
        v4f A0 = ar[0], A1 = ar[1], A2 = ar[2], A3 = ar[3];
        v4f B0 = ar[4], B1 = ar[5], B2 = ar[6], B3 = ar[7];
        v2f xa = *(const v2f*)&pre[(size_t)sa * 128 + c0];
        v2f xb = *(const v2f*)&pre[(size_t)sb * 128 + c0];
        v2f ea = eb, eb2 = eb;
        ea  = __builtin_elementwise_fma(sp(A0.x), wE[0], ea);
        eb2 = __builtin_elementwise_fma(sp(B0.x), wE[0], eb2);
        ea  = __builtin_elementwise_fma(sp(A0.y), wE[1], ea);
        eb2 = __builtin_elementwise_fma(sp(B0.y), wE[1], eb2);
        ea  = __builtin_elementwise_fma(sp(A0.z), wE[2], ea);
        eb2 = __builtin_elementwise_fma(sp(B0.z), wE[2], eb2);
        ea  = __builtin_elementwise_fma(sp(A0.w), wE[3], ea);
        eb2 = __builtin_elementwise_fma(sp(B0.w), wE[3], eb2);
        ea  = __builtin_elementwise_fma(sp(A1.x), wE[4], ea);
        eb2 = __builtin_elementwise_fma(sp(B1.x), wE[4], eb2);
        ea  = __builtin_elementwise_fma(sp(A1.y), wE[5], ea);
        eb2 = __builtin_elementwise_fma(sp(B1.y), wE[5], eb2);
        ea  = __builtin_elementwise_fma(sp(A1.z), wE[6], ea);
        eb2 = __builtin_elementwise_fma(sp(B1.z), wE[6], eb2);
        ea  = __builtin_elementwise_fma(sp(A1.w), wE[7], ea);
        eb2 = __builtin_elementwise_fma(sp(B1.w), wE[7], eb2);
        ea  = __builtin_elementwise_fma(sp(A2.x), wE[8], ea);
        eb2 = __builtin_elementwise_fma(sp(B2.x), wE[8], eb2);
        ea  = __builtin_elementwise_fma(sp(A2.y), wE[9], ea);
        eb2 = __builtin_elementwise_fma(sp(B2.y), wE[9], eb2);
        ea  = __builtin_elementwise_fma(sp(A2.z), wE[10], ea);
        eb2 = __builtin_elementwise_fma(sp(B2.z), wE[10], eb2);
        ea  = __builtin_elementwise_fma(sp(A2.w), wE[11], ea);
        eb2 = __builtin_elementwise_fma(sp(B2.w), wE[11], eb2);
        ea  = __builtin_elementwise_fma(sp(A3.x), wE[12], ea);
        eb2 = __builtin_elementwise_fma(sp(B3.x), wE[12], eb2);
        ea  = __builtin_elementwise_fma(sp(A3.y), wE[13], ea);
        eb2 = __builtin_elementwise_fma(sp(B3.y), wE[13], eb2);
        ea  = __builtin_elementwise_fma(sp(A3.z), wE[14], ea);
        eb2 = __builtin_elementwise_fma(sp(B3.z), wE[14], eb2);
        ea  = __builtin_elementwise_fma(sp(A3.w), wE[15], ea);
        eb2 = __builtin_elementwise_fma(sp(B3.w), wE[15], eb2);
        float mgax = fmaxf(xa.x + ea.x, 0.f) + EPS_MSG;
        float mgay = fmaxf(xa.y + ea.y, 0.f) + EPS_MSG;
        float mgbx = fmaxf(xb.x + eb2.x, 0.f) + EPS_MSG;
        float mgby = fmaxf(xb.y + eb2.y, 0.f) + EPS_MSG;
        float exa = __expf(mgax * t);
        float eya = __expf(mgay * t);
        float exb = __expf(mgbx * t);
        float eyb = __expf(mgby * t);
        sx += exa + exb;
        sy += eya + eyb;
        wx = fmaf(exa, mgax, wx); wx = fmaf(exb, mgbx, wx);
        wy = fmaf(eya, mgay, wy); wy = fmaf(eyb, mgby, wy);
    }
    if (i < i1) {
        int iu = __builtin_amdgcn_readfirstlane(i);
        int sn = src_perm[iu];
        const v4f* ar = (const v4f*)(attr_perm + (size_t)iu * 16);
        v4f A0 = ar[0], A1 = ar[1], A2 = ar[2], A3 = ar[3];
        v2f xv = *(const v2f*)&pre[(size_t)sn * 128 + c0];
        v2f ea = eb;
        ea = __builtin_elementwise_fma(sp(A0.x), wE[0], ea);
        ea = __builtin_elementwise_fma(sp(A0.y), wE[1], ea);
        ea = __builtin_elementwise_fma(sp(A0.z), wE[2], ea);
        ea = __builtin_elementwise_fma(sp(A0.w), wE[3], ea);
        ea = __builtin_elementwise_fma(sp(A1.x), wE[4], ea);
        ea = __builtin_elementwise_fma(sp(A1.y), wE[5], ea);
        ea = __builtin_elementwise_fma(sp(A1.z), wE[6], ea);
        ea = __builtin_elementwise_fma(sp(A1.w), wE[7], ea);
        ea = __builtin_elementwise_fma(sp(A2.x), wE[8], ea);
        ea = __builtin_elementwise_fma(sp(A2.y), wE[9], ea);
        ea = __builtin_elementwise_fma(sp(A2.z), wE[10], ea);
        ea = __builtin_elementwise_fma(sp(A2.w), wE[11], ea);
        ea = __builtin_elementwise_fma(sp(A3.x), wE[12], ea);
        ea = __builtin_elementwise_fma(sp(A3.y), wE[13], ea);
        ea = __builtin_elementwise_fma(sp(A3.z), wE[14], ea);
        ea = __builtin_elementwise_fma(sp(A3.w), wE[15], ea);
        float mgx = fmaxf(xv.x + ea.x, 0.f) + EPS_MSG;
        float mgy = fmaxf(xv.y + ea.y, 0.f) + EPS_MSG;
        float ex = __expf(mgx * t);
        float ey = __expf(mgy * t);
        sx += ex; sy += ey;
        wx = fmaf(ex, mgx, wx);
        wy = fmaf(ey, mgy, wy);
    }
    float ax = (sx > 0.f) ? wx / sx : 0.f;
    float ay = (sy > 0.f) ? wy / sy : 0.f;
    v2f o; o.x = ax + xself.x; o.y = ay + xself.y;
    *(v2f*)&convout[(size_t)node * 128 + c0] = o;
}

// ---------------------------------------------------------------- fused MLP (R3 version: 32-node tile, LDS-staged)
template <int RES>
__global__ __launch_bounds__(256)
void mlp_kernel(const float* __restrict__ convin, const float* __restrict__ W1,
                const float* __restrict__ b1, const float* __restrict__ g1,
                const float* __restrict__ be1, const float* __restrict__ W2,
                const float* __restrict__ b2, const float* __restrict__ xold,
                float* __restrict__ xnew, int N) {
    __shared__ __align__(16) float Xa[32][128];
    __shared__ __align__(16) float Xh[32][256];
    int tid = threadIdx.x;
    int node0 = blockIdx.x * 32;
    {
        int row = tid >> 3;
        int col = (tid & 7) * 16;
        float4 v0 = make_float4(0, 0, 0, 0), v1 = v0, v2 = v0, v3 = v0;
        if (node0 + row < N) {
            const float4* sp_ = (const float4*)&convin[(size_t)(node0 + row) * 128 + col];
            v0 = sp_[0]; v1 = sp_[1]; v2 = sp_[2]; v3 = sp_[3];
        }
        *(float4*)&Xa[row][col + 0] = v0;
        *(float4*)&Xa[row][col + 4] = v1;
        *(float4*)&Xa[row][col + 8] = v2;
        *(float4*)&Xa[row][col + 12] = v3;
    }
    __syncthreads();
    // GEMM1: 32x256 = Xa(32x128) @ W1(128x256); wave ty owns 8 rows, lane owns 4 cols
    {
        int tx = tid & 63, ty = tid >> 6;
        int c = tx * 4;
        v2f b1a = *(const v2f*)&b1[c];
        v2f b1b = *(const v2f*)&b1[c + 2];
        v2f acc[8][2];
#pragma unroll
        for (int i = 0; i < 8; ++i) { acc[i][0] = b1a; acc[i][1] = b1b; }
        for (int k = 0; k < 128; k += 4) {
            v4f W0 = *(const v4f*)&W1[(size_t)(k + 0) * 256 + c];
            v4f W1r = *(const v4f*)&W1[(size_t)(k + 1) * 256 + c];
            v4f W2r = *(const v4f*)&W1[(size_t)(k + 2) * 256 + c];
            v4f W3r = *(const v4f*)&W1[(size_t)(k + 3) * 256 + c];
#pragma unroll
            for (int i = 0; i < 8; ++i) {
                v4f xv = *(const v4f*)&Xa[ty * 8 + i][k];
                acc[i][0] = __builtin_elementwise_fma(sp(xv.x), W0.xy, acc[i][0]);
                acc[i][1] = __builtin_elementwise_fma(sp(xv.x), W0.zw, acc[i][1]);
                acc[i][0] = __builtin_elementwise_fma(sp(xv.y), W1r.xy, acc[i][0]);
                acc[i][1] = __builtin_elementwise_fma(sp(xv.y), W1r.zw, acc[i][1]);
                acc[i][0] = __builtin_elementwise_fma(sp(xv.z), W2r.xy, acc[i][0]);
                acc[i][1] = __builtin_elementwise_fma(sp(xv.z), W2r.zw, acc[i][1]);
                acc[i][0] = __builtin_elementwise_fma(sp(xv.w), W3r.xy, acc[i][0]);
                acc[i][1] = __builtin_elementwise_fma(sp(xv.w), W3r.zw, acc[i][1]);
            }
        }
        // LN(256) + relu per row (reduce across the 64 lanes of this wave)
        v2f g1a = *(const v2f*)&g1[c];
        v2f g1b = *(const v2f*)&g1[c + 2];
        v2f bea = *(const v2f*)&be1[c];
        v2f beb = *(const v2f*)&be1[c + 2];
#pragma unroll
        for (int i = 0; i < 8; ++i) {
            float s = acc[i][0].x + acc[i][0].y + acc[i][1].x + acc[i][1].y;
            float q = acc[i][0].x * acc[i][0].x + acc[i][0].y * acc[i][0].y +
                      acc[i][1].x * acc[i][1].x + acc[i][1].y * acc[i][1].y;
#pragma unroll
            for (int m = 1; m < 64; m <<= 1) { s += __shfl_xor(s, m, 64); q += __shfl_xor(q, m, 64); }
            float mu = s * (1.f / 256.f);
            float var = q * (1.f / 256.f) - mu * mu;
            float rs = rsqrtf(var + 1e-5f);
            float h0 = fmaxf((acc[i][0].x - mu) * rs * g1a.x + bea.x, 0.f);
            float h1 = fmaxf((acc[i][0].y - mu) * rs * g1a.y + bea.y, 0.f);
            float h2 = fmaxf((acc[i][1].x - mu) * rs * g1b.x + beb.x, 0.f);
            float h3 = fmaxf((acc[i][1].y - mu) * rs * g1b.y + beb.y, 0.f);
            *(float4*)&Xh[ty * 8 + i][c] = make_float4(h0, h1, h2, h3);
        }
    }
    __syncthreads();
    // GEMM2: 32x128 = Xh(32x256) @ W2(256x128); 32-lane group rg owns 4 rows, lane owns 4 cols
    {
        int tx2 = tid & 31, rg = tid >> 5;
        int c2 = tx2 * 4;
        v2f b2a = *(const v2f*)&b2[c2];
        v2f b2b = *(const v2f*)&b2[c2 + 2];
        v2f acc[4][2];
#pragma unroll
        for (int i = 0; i < 4; ++i) { acc[i][0] = b2a; acc[i][1] = b2b; }
        for (int k = 0; k < 256; k += 4) {
            v4f W0 = *(const v4f*)&W2[(size_t)(k + 0) * 128 + c2];
            v4f W1r = *(const v4f*)&W2[(size_t)(k + 1) * 128 + c2];
            v4f W2r = *(const v4f*)&W2[(size_t)(k + 2) * 128 + c2];
            v4f W3r = *(const v4f*)&W2[(size_t)(k + 3) * 128 + c2];
#pragma unroll
            for (int i = 0; i < 4; ++i) {
                v4f xv = *(const v4f*)&Xh[rg * 4 + i][k];
                acc[i][0] = __builtin_elementwise_fma(sp(xv.x), W0.xy, acc[i][0]);
                acc[i][1] = __builtin_elementwise_fma(sp(xv.x), W0.zw, acc[i][1]);
                acc[i][0] = __builtin_elementwise_fma(sp(xv.y), W1r.xy, acc[i][0]);
                acc[i][1] = __builtin_elementwise_fma(sp(xv.y), W1r.zw, acc[i][1]);
                acc[i][0] = __builtin_elementwise_fma(sp(xv.z), W2r.xy, acc[i][0]);
                acc[i][1] = __builtin_elementwise_fma(sp(xv.z), W2r.zw, acc[i][1]);
                acc[i][0] = __builtin_elementwise_fma(sp(xv.w), W3r.xy, acc[i][0]);
                acc[i][1] = __builtin_elementwise_fma(sp(xv.w), W3r.zw, acc[i][1]);
            }
        }
#pragma unroll
        for (int i = 0; i < 4; ++i) {
            int row = node0 + rg * 4 + i;
            if (row < N) {
                float4 o = make_float4(acc[i][0].x, acc[i][0].y, acc[i][1].x, acc[i][1].y);
                if (RES) {
                    float4 xo = *(const float4*)&xold[(size_t)row * 128 + c2];
                    o.x += xo.x; o.y += xo.y; o.z += xo.z; o.w += xo.w;
                }
                *(float4*)&xnew[(size_t)row * 128 + c2] = o;
            }
        }
    }
}

// ---------------------------------------------------------------- head
__global__ __launch_bounds__(256)
void head_kernel(const float* __restrict__ pre, const float* __restrict__ gf,
                 const float* __restrict__ W0, const float* __restrict__ b0,
                 const float* __restrict__ W1h, const float* __restrict__ b1h,
                 float* __restrict__ out, int N) {
    __shared__ __align__(16) float V[8][132];
    int tid = threadIdx.x;
    int node0 = blockIdx.x * 8;
    int tx = tid & 31, rg = tid >> 5;
    {
        int col = tx * 4;
        float4 v = make_float4(0, 0, 0, 0);
        int node = node0 + rg;
        if (node < N) v = *(const float4*)&pre[(size_t)node * 128 + col];
        *(float4*)&V[rg][col] = v;
        if (tx == 0) {
            int a = node / 1000;
            int i0 = 2 * a, i1 = 2 * a + 1;
            float f0 = 0.f, f1 = 0.f;
            if (node < N) {
                f0 = (i0 < 50) ? gf[i0 * 2] : gf[(i0 - 50) * 2 + 1];
                f1 = (i1 < 50) ? gf[i1 * 2] : gf[(i1 - 50) * 2 + 1];
            }
            V[rg][128] = f0;
            V[rg][129] = f1;
        }
    }
    __syncthreads();
    int c = tx * 4;
    float4 b0v = *(const float4*)&b0[c];
    float a0 = b0v.x, a1 = b0v.y, a2 = b0v.z, a3 = b0v.w;
    for (int k = 0; k < 130; ++k) {
        float vk = V[rg][k];
        float4 w = *(const float4*)&W0[k * 128 + c];
        a0 = fmaf(vk, w.x, a0);
        a1 = fmaf(vk, w.y, a1);
        a2 = fmaf(vk, w.z, a2);
        a3 = fmaf(vk, w.w, a3);
    }
    a0 = fmaxf(a0, 0.f); a1 = fmaxf(a1, 0.f); a2 = fmaxf(a2, 0.f); a3 = fmaxf(a3, 0.f);
    float4 wh = *(const float4*)&W1h[c];
    float p = a0 * wh.x + a1 * wh.y + a2 * wh.z + a3 * wh.w;
#pragma unroll
    for (int m = 1; m < 32; m <<= 1) p += __shfl_xor(p, m, 64);
    int node = node0 + rg;
    if (tx == 0 && node < N) out[node] = p + b1h[0];
}

// ---------------------------------------------------------------- launch
extern "C" void kernel_launch(void* const* d_in, const int* in_sizes, int n_in,
                              void* d_out, int out_size, void* d_ws, size_t ws_size,
                              hipStream_t stream) {
    const float* x_in    = (const float*)d_in[0];
    const int*   ei      = (const int*)d_in[1];
    const float* edge_attr = (const float*)d_in[2];
    const float* gf      = (const float*)d_in[3];
    const float* node_W  = (const float*)d_in[4];
    const float* node_b  = (const float*)d_in[5];
    const float* edge_W  = (const float*)d_in[6];
    const float* edge_b  = (const float*)d_in[7];
    const float* ts      = (const float*)d_in[8];
    const float* W1s     = (const float*)d_in[9];
    const float* b1s     = (const float*)d_in[10];
    const float* g1s     = (const float*)d_in[11];
    const float* be1s    = (const float*)d_in[12];
    const float* W2s     = (const float*)d_in[13];
    const float* b2s     = (const float*)d_in[14];
    const float* ln_gs   = (const float*)d_in[15];
    const float* ln_bs   = (const float*)d_in[16];
    const float* hW0     = (const float*)d_in[17];
    const float* hb0     = (const float*)d_in[18];
    const float* hW1     = (const float*)d_in[19];
    const float* hb1     = (const float*)d_in[20];

    const int N = in_sizes[0] / 64;
    const int E = in_sizes[1] / 2;
    const int NB = (N + 1023) / 1024;

    char* ws = (char*)d_ws;
    size_t off = 0;
    auto alloc = [&](size_t bytes) -> void* {
        void* p = ws + off;
        off = (off + bytes + 255) & ~(size_t)255;
        return p;
    };
    float* X     = (float*)alloc((size_t)N * 128 * 4);
    float* PRE   = (float*)alloc((size_t)N * 128 * 4);
    float* CONV  = (float*)alloc((size_t)N * 128 * 4);
    float* ATTRP = (float*)alloc((size_t)E * 16 * 4);
    int* SRCP    = (int*)alloc((size_t)E * 4);
    int* DEG     = (int*)alloc((size_t)N * 4);
    int* FILL    = (int*)alloc((size_t)N * 4);
    int* OFFS    = (int*)alloc((size_t)(N + 1) * 4);
    int* BSUM    = (int*)alloc((size_t)(NB + 1) * 4);

    // CSR build (per call; deterministic set of work)
    zero2_kernel<<<(N + 255) / 256, 256, 0, stream>>>(DEG, FILL, N);
    deg_kernel<<<(E + 255) / 256, 256, 0, stream>>>(ei, DEG, E);
    scan1_kernel<<<NB, 1024, 0, stream>>>(DEG, OFFS, BSUM, N);
    scan2_kernel<<<1, 64, 0, stream>>>(BSUM, NB);
    scan3_kernel<<<(N + 256) / 256, 256, 0, stream>>>(OFFS, BSUM, N);
    scatter_kernel<<<(E + 255) / 256, 256, 0, stream>>>(ei, edge_attr, OFFS, FILL, SRCP, ATTRP, E);

    encode_kernel<<<(N + 31) / 32, 256, 0, stream>>>(x_in, node_W, node_b, X, N);

    for (int layer = 0; layer < 4; ++layer) {
        const float* pre = X;
        if (layer > 0) {
            ln_relu_kernel<<<(N + 3) / 4, 256, 0, stream>>>(X, ln_gs + 128 * layer, ln_bs + 128 * layer, PRE, N);
            pre = PRE;
        }
        conv_kernel<<<(N + 3) / 4, 256, 0, stream>>>(pre, ATTRP, SRCP, OFFS, edge_W, edge_b, ts, layer, CONV, N);
        const float* W1 = W1s + (size_t)layer * 128 * 256;
        const float* W2 = W2s + (size_t)layer * 256 * 128;
        if (layer == 0)
            mlp_kernel<0><<<(N + 31) / 32, 256, 0, stream>>>(CONV, W1, b1s + layer * 256, g1s + layer * 256,
                                                             be1s + layer * 256, W2, b2s + layer * 128, X, X, N);
        else
            mlp_kernel<1><<<(N + 31) / 32, 256, 0, stream>>>(CONV, W1, b1s + layer * 256, g1s + layer * 256,
                                                             be1s + layer * 256, W2, b2s + layer * 128, X, X, N);
    }

    ln_relu_kernel<<<(N + 3) / 4, 256, 0, stream>>>(X, ln_gs, ln_bs, PRE, N);
    head_kernel<<<(N + 7) / 8, 256, 0, stream>>>(PRE, gf, hW0, hb0, hW1, hb1, (float*)d_out, N);
}